// Round 1
// baseline (4952.821 us; speedup 1.0000x reference)
//
#include <hip/hip_runtime.h>
#include <hip/hip_fp16.h>

typedef _Float16 f16;
typedef _Float16 half8 __attribute__((ext_vector_type(8)));
typedef _Float16 f16x2 __attribute__((ext_vector_type(2)));
typedef float floatx4 __attribute__((ext_vector_type(4)));

#define MFMA_F16(a,b,c) __builtin_amdgcn_mfma_f32_16x16x32_f16((a),(b),(c),0,0,0)

namespace cfg {
constexpr int V=5000, E=256, H=512, T=128, NB=64, G4=2048, VP=5120, NSTEPS=255;
// ws byte offsets (all 16B aligned)
constexpr size_t XPE = 0;                                  // f16 [V][2048] paired-col layout
constexpr size_t XPD = XPE + (size_t)V*G4*2;
constexpr size_t W0E = XPD + (size_t)V*G4*2;               // f16 [64][2048][8]  (Whh0 pack)
constexpr size_t W0D = W0E + (size_t)64*G4*8*2;
constexpr size_t W1E = W0D + (size_t)64*G4*8*2;            // f16 [128][2048][8] ([Wih1;Whh1] pack)
constexpr size_t W1D = W1E + (size_t)128*G4*8*2;
constexpr size_t WT0E= W1D + (size_t)128*G4*8*2;           // f16 [32][2048][8]  (Wih0 pack)
constexpr size_t WT0D= WT0E + (size_t)32*G4*8*2;
constexpr size_t FCW = WT0D + (size_t)32*G4*8*2;           // f16 [64][5120][8]  (fc_W pack)
constexpr size_t EMBE= FCW + (size_t)64*VP*8*2;            // f16 [V][256]
constexpr size_t EMBD= EMBE + (size_t)V*E*2;
constexpr size_t B0E = EMBD + (size_t)V*E*2;               // f32 [2048] permuted
constexpr size_t B0D = B0E + (size_t)G4*4;
constexpr size_t B1E = B0D + (size_t)G4*4;
constexpr size_t B1D = B1E + (size_t)G4*4;
constexpr size_t H0B = B1D + (size_t)G4*4;                 // f16 [255][64][512]
constexpr size_t H1B = H0B + (size_t)NSTEPS*NB*H*2;        // f16 [255][64][512]
constexpr size_t CNT = H1B + (size_t)NSTEPS*NB*H*2;        // int c0[256], c1[256]
}

__device__ __forceinline__ int gcol0(int p){ int s=p&31, w=p>>5; return ((s>>3)*512) + w*8 + (s&7); }
__device__ __forceinline__ int gcol1(int p){ int s=p&15, w=p>>4; return ((s>>2)*512) + w*4 + (s&3); }
__device__ __forceinline__ float sigf(float x){ return 1.0f/(1.0f + __expf(-x)); }
__device__ __forceinline__ half8 ldh8(const f16* p){ return *(const half8*)p; }

// ---------------- init: zero out[0,:,:] and counters ----------------
__global__ void init_kernel(float* out, char* ws){
  int i = blockIdx.x*256 + threadIdx.x;
  if (i < 320000) out[i] = 0.0f;
  if (i < 512) ((int*)(ws + cfg::CNT))[i] = 0;
}

// ---------------- pack/convert weights ----------------
__global__ void pack_kernel(char* ws,
    const float* embE, const float* embD,
    const float* eWih0, const float* eWhh0, const float* eb0,
    const float* eWih1, const float* eWhh1, const float* eb1,
    const float* dWih0, const float* dWhh0, const float* db0,
    const float* dWih1, const float* dWhh1, const float* db1,
    const float* fcW)
{
  long long idx = (long long)blockIdx.x*256 + threadIdx.x;
  if (idx < 1280000) { ((f16*)(ws+cfg::EMBE))[idx] = (f16)embE[idx]; return; }
  idx -= 1280000;
  if (idx < 1280000) { ((f16*)(ws+cfg::EMBD))[idx] = (f16)embD[idx]; return; }
  idx -= 1280000;
  if (idx < 2097152) { // Whh0 packs enc+dec: [k8][2048][8]
    int which = idx >= 1048576; long long t = idx & 1048575;
    int j = t&7, p = (int)((t>>3)&2047), k8 = (int)(t>>14);
    const float* W = which ? dWhh0 : eWhh0;
    f16* O = (f16*)(ws + (which ? cfg::W0D : cfg::W0E));
    O[t] = (f16)W[(long long)gcol0(p)*512 + k8*8 + j]; return; }
  idx -= 2097152;
  if (idx < 4194304) { // [Wih1;Whh1] packs: [k8(128)][2048][8]
    int which = idx >= 2097152; long long t = idx & 2097151;
    int j = t&7, p = (int)((t>>3)&2047), k8 = (int)(t>>14);
    int gc = gcol1(p); int k = k8*8 + j;
    const float* Wi = which ? dWih1 : eWih1;
    const float* Wh = which ? dWhh1 : eWhh1;
    f16* O = (f16*)(ws + (which ? cfg::W1D : cfg::W1E));
    O[t] = (f16)(k < 512 ? Wi[(long long)gc*512 + k] : Wh[(long long)gc*512 + (k-512)]); return; }
  idx -= 4194304;
  if (idx < 1048576) { // Wih0 packs: [k8(32)][2048][8]
    int which = idx >= 524288; long long t = idx & 524287;
    int j = t&7, p = (int)((t>>3)&2047), k8 = (int)(t>>14);
    const float* W = which ? dWih0 : eWih0;
    f16* O = (f16*)(ws + (which ? cfg::WT0D : cfg::WT0E));
    O[t] = (f16)W[(long long)gcol0(p)*256 + k8*8 + j]; return; }
  idx -= 1048576;
  if (idx < 2621440) { // fcW pack: [k8(64)][5120][8]
    long long t = idx; int j = t&7; int n = (int)((t>>3)%5120); int k8 = (int)(t/40960);
    ((f16*)(ws+cfg::FCW))[t] = (f16)(n < 5000 ? fcW[(long long)n*512 + k8*8 + j] : 0.0f); return; }
  idx -= 2621440;
  if (idx < 8192) {
    int which = (int)(idx>>11); int p = (int)(idx&2047);
    if      (which==0) ((float*)(ws+cfg::B0E))[p] = eb0[gcol0(p)];
    else if (which==1) ((float*)(ws+cfg::B0D))[p] = db0[gcol0(p)];
    else if (which==2) ((float*)(ws+cfg::B1E))[p] = eb1[gcol1(p)];
    else               ((float*)(ws+cfg::B1D))[p] = db1[gcol1(p)];
  }
}

// ---------------- XP tables: XP[v] = emb[v] @ Wih0^T + b0 ----------------
__global__ __launch_bounds__(256) void table_kernel(char* ws){
  int which = blockIdx.z;
  const f16* A  = (const f16*)(ws + (which ? cfg::EMBD : cfg::EMBE));
  const f16* Bp = (const f16*)(ws + (which ? cfg::WT0D : cfg::WT0E));
  const float* b0p = (const float*)(ws + (which ? cfg::B0D : cfg::B0E));
  f16* XP = (f16*)(ws + (which ? cfg::XPD : cfg::XPE));
  int lane = threadIdx.x & 63, wave = threadIdx.x >> 6;
  int m15 = lane & 15, q = lane >> 4;
  int wm = wave >> 1, wn = wave & 1;
  int rowbase = blockIdx.x*128 + wm*64;
  int pbase   = blockIdx.y*128 + wn*64;
  floatx4 zz = {0.f,0.f,0.f,0.f};
  floatx4 acc[4][4];
  #pragma unroll
  for (int mt=0; mt<4; ++mt)
    #pragma unroll
    for (int nt=0; nt<4; ++nt) acc[mt][nt] = zz;
  int rows[4];
  #pragma unroll
  for (int mt=0; mt<4; ++mt){ int r = rowbase + mt*16 + m15; rows[mt] = r < 5000 ? r : 4999; }
  for (int ki=0; ki<8; ++ki){
    half8 a[4], b[4];
    #pragma unroll
    for (int mt=0; mt<4; ++mt) a[mt] = ldh8(A + (size_t)rows[mt]*256 + ki*32 + q*8);
    #pragma unroll
    for (int nt=0; nt<4; ++nt) b[nt] = ldh8(Bp + ((size_t)(ki*4+q)*2048 + pbase + nt*16 + m15)*8);
    #pragma unroll
    for (int mt=0; mt<4; ++mt)
      #pragma unroll
      for (int nt=0; nt<4; ++nt) acc[mt][nt] = MFMA_F16(a[mt], b[nt], acc[mt][nt]);
  }
  #pragma unroll
  for (int nt=0; nt<4; ++nt){
    int p = pbase + nt*16 + m15;
    float bb = b0p[p];
    int s = p & 31;
    int tcol = (p>>5)*32 + (s < 16 ? s*2 : (s-16)*2 + 1);  // paired [i_j,g_j] / [f_j,o_j]
    #pragma unroll
    for (int mt=0; mt<4; ++mt)
      #pragma unroll
      for (int r=0; r<4; ++r){
        int v = rowbase + mt*16 + q*4 + r;
        if (v < 5000) XP[(size_t)v*2048 + tcol] = (f16)(acc[mt][nt][r] + bb);
      }
  }
}

// ---------------- persistent recurrence kernel ----------------
__device__ __forceinline__ void wait_ge(int* p, int target){
  while (__hip_atomic_load(p, __ATOMIC_RELAXED, __HIP_MEMORY_SCOPE_AGENT) < target)
    __builtin_amdgcn_s_sleep(2);
}

__global__ __launch_bounds__(256,1) void seq_kernel(char* ws, const int* src, const int* trg){
  __shared__ floatx4 lds4[2048];   // 32 KiB reduction buffer
  int lane = threadIdx.x & 63, wave = threadIdx.x >> 6;
  int m15 = lane & 15, q = lane >> 4;
  int* c0 = (int*)(ws + cfg::CNT);
  int* c1 = c0 + 256;
  f16* H0 = (f16*)(ws + cfg::H0B);
  f16* H1 = (f16*)(ws + cfg::H1B);

  if (blockIdx.x < 64) {
    // ======== team0: layer-0 chain (owns h-cols [8w, 8w+8)) ========
    int w = blockIdx.x;
    float cst[4] = {0.f,0.f,0.f,0.f};   // c0 state: lanes m15<8, rows wave*16+q*4+r
    for (int seg=0; seg<2; ++seg){
      const f16* Wp = (const f16*)(ws + (seg ? cfg::W0D : cfg::W0E));
      const f16* XP = (const f16*)(ws + (seg ? cfg::XPD : cfg::XPE));
      const int* tok = seg ? trg : src;
      int nsteps = seg ? 127 : 128, gbase = seg ? 128 : 0;
      half8 breg[4][2];
      #pragma unroll
      for (int ki=0; ki<4; ++ki)
        #pragma unroll
        for (int nt=0; nt<2; ++nt)
          breg[ki][nt] = ldh8(Wp + ((size_t)(wave*16 + ki*4 + q)*2048 + w*32 + nt*16 + m15)*8);
      for (int i=0; i<nsteps; ++i){
        int g = gbase + i;
        if (threadIdx.x == 0 && g > 0){ wait_ge(c0 + g - 1, 64); __threadfence(); }
        __syncthreads();
        floatx4 zz = {0.f,0.f,0.f,0.f};
        floatx4 acc[4][2];
        #pragma unroll
        for (int mt=0; mt<4; ++mt){ acc[mt][0]=zz; acc[mt][1]=zz; }
        if (g > 0){
          const f16* hp = H0 + (size_t)(g-1)*32768;
          #pragma unroll
          for (int ki=0; ki<4; ++ki){
            int kk = wave*128 + ki*32 + q*8;
            half8 a[4];
            #pragma unroll
            for (int mt=0; mt<4; ++mt) a[mt] = ldh8(hp + (mt*16 + m15)*512 + kk);
            #pragma unroll
            for (int mt=0; mt<4; ++mt){
              acc[mt][0] = MFMA_F16(a[mt], breg[ki][0], acc[mt][0]);
              acc[mt][1] = MFMA_F16(a[mt], breg[ki][1], acc[mt][1]);
            }
          }
        }
        // cross-wave K reduction via LDS
        #pragma unroll
        for (int mt=0; mt<4; ++mt){
          lds4[((mt*4+wave)*2+0)*64 + lane] = acc[mt][0];
          lds4[((mt*4+wave)*2+1)*64 + lane] = acc[mt][1];
        }
        __syncthreads();
        float gs0[4] = {0,0,0,0}, gs1[4] = {0,0,0,0};
        #pragma unroll
        for (int u=0; u<4; ++u){
          floatx4 t0 = lds4[((wave*4+u)*2+0)*64 + lane];
          floatx4 t1 = lds4[((wave*4+u)*2+1)*64 + lane];
          #pragma unroll
          for (int r=0; r<4; ++r){ gs0[r]+=t0[r]; gs1[r]+=t1[r]; }
        }
        int4 tk = *(const int4*)(tok + i*64 + wave*16 + q*4);
        int tks[4] = {tk.x, tk.y, tk.z, tk.w};
        #pragma unroll
        for (int r=0; r<4; ++r){
          f16x2 xp = *(const f16x2*)(XP + (size_t)tks[r]*2048 + w*32 + m15*2);
          gs0[r] += (float)xp[0];  // i (m15<8) / f (m15>=8)
          gs1[r] += (float)xp[1];  // g (m15<8) / o (m15>=8)
        }
        float fv[4], ov[4];
        #pragma unroll
        for (int r=0; r<4; ++r){ fv[r] = __shfl_xor(gs0[r], 8); ov[r] = __shfl_xor(gs1[r], 8); }
        if (m15 < 8){
          f16* hout = H0 + (size_t)g*32768;
          #pragma unroll
          for (int r=0; r<4; ++r){
            float c = sigf(fv[r])*cst[r] + sigf(gs0[r])*tanhf(gs1[r]);
            cst[r] = c;
            float h = sigf(ov[r])*tanhf(c);
            hout[(wave*16 + q*4 + r)*512 + w*8 + m15] = (f16)h;
          }
        }
        __syncthreads();
        if (threadIdx.x == 0){
          __threadfence();
          __hip_atomic_fetch_add(c0 + g, 1, __ATOMIC_RELEASE, __HIP_MEMORY_SCOPE_AGENT);
        }
      }
    }
  } else {
    // ======== team1: layer-1, trails one step (owns h-cols [4w, 4w+4)) ========
    int w = blockIdx.x - 64;   // 0..127
    float cst[4] = {0.f,0.f,0.f,0.f};   // c1 state: lanes m15<4
    for (int seg=0; seg<2; ++seg){
      const f16* Wp = (const f16*)(ws + (seg ? cfg::W1D : cfg::W1E));
      const float* bp = (const float*)(ws + (seg ? cfg::B1D : cfg::B1E));
      int nsteps = seg ? 127 : 128, gbase = seg ? 128 : 0;
      half8 breg[8];
      #pragma unroll
      for (int ki=0; ki<8; ++ki)
        breg[ki] = ldh8(Wp + ((size_t)(wave*32 + ki*4 + q)*2048 + w*16 + m15)*8);
      float b1v = bp[w*16 + m15];
      for (int i=0; i<nsteps; ++i){
        int g = gbase + i;
        if (threadIdx.x == 0){
          wait_ge(c0 + g, 64);
          if (g > 0) wait_ge(c1 + g - 1, 128);
          __threadfence();
        }
        __syncthreads();
        floatx4 zz = {0.f,0.f,0.f,0.f};
        floatx4 acc[4];
        #pragma unroll
        for (int mt=0; mt<4; ++mt) acc[mt] = zz;
        bool active = (wave < 2) || (g > 0);
        if (active){
          const f16* hp = (wave < 2) ? (H0 + (size_t)g*32768) : (H1 + (size_t)(g-1)*32768);
          #pragma unroll
          for (int ki=0; ki<8; ++ki){
            int kk = (wave & 1)*256 + ki*32 + q*8;
            half8 a[4];
            #pragma unroll
            for (int mt=0; mt<4; ++mt) a[mt] = ldh8(hp + (mt*16 + m15)*512 + kk);
            #pragma unroll
            for (int mt=0; mt<4; ++mt) acc[mt] = MFMA_F16(a[mt], breg[ki], acc[mt]);
          }
        }
        #pragma unroll
        for (int mt=0; mt<4; ++mt) lds4[(mt*4+wave)*64 + lane] = acc[mt];
        __syncthreads();
        float gs[4] = {b1v, b1v, b1v, b1v};
        #pragma unroll
        for (int u=0; u<4; ++u){
          floatx4 t0 = lds4[(wave*4+u)*64 + lane];
          #pragma unroll
          for (int r=0; r<4; ++r) gs[r] += t0[r];
        }
        float f4[4], g8[4], o12[4];
        #pragma unroll
        for (int r=0; r<4; ++r){
          f4[r]  = __shfl_xor(gs[r], 4);
          g8[r]  = __shfl_xor(gs[r], 8);
          o12[r] = __shfl_xor(gs[r], 12);
        }
        if (m15 < 4){
          f16* hout = H1 + (size_t)g*32768;
          #pragma unroll
          for (int r=0; r<4; ++r){
            float c = sigf(f4[r])*cst[r] + sigf(gs[r])*tanhf(g8[r]);
            cst[r] = c;
            float h = sigf(o12[r])*tanhf(c);
            hout[(wave*16 + q*4 + r)*512 + w*4 + m15] = (f16)h;
          }
        }
        __syncthreads();
        if (threadIdx.x == 0){
          __threadfence();
          __hip_atomic_fetch_add(c1 + g, 1, __ATOMIC_RELEASE, __HIP_MEMORY_SCOPE_AGENT);
        }
      }
    }
  }
}

// ---------------- fc projection + vocab_sim mask epilogue ----------------
__global__ __launch_bounds__(256) void fc_kernel(char* ws, const int* src, const float* vs,
                                                 const float* fcb, float* out){
  const f16* H1 = (const f16*)(ws + cfg::H1B);
  const f16* Bp = (const f16*)(ws + cfg::FCW);
  int lane = threadIdx.x & 63, wave = threadIdx.x >> 6;
  int m15 = lane & 15, q = lane >> 4;
  int wm = wave >> 1, wn = wave & 1;
  int rowbase = blockIdx.x*128 + wm*64;
  int vbase   = blockIdx.y*128 + wn*64;
  floatx4 zz = {0.f,0.f,0.f,0.f};
  floatx4 acc[4][4];
  #pragma unroll
  for (int mt=0; mt<4; ++mt)
    #pragma unroll
    for (int nt=0; nt<4; ++nt) acc[mt][nt] = zz;
  int rows[4];
  #pragma unroll
  for (int mt=0; mt<4; ++mt){ int r = rowbase + mt*16 + m15; rows[mt] = r < 8128 ? r : 8127; }
  for (int ki=0; ki<16; ++ki){
    half8 a[4], b[4];
    #pragma unroll
    for (int mt=0; mt<4; ++mt)
      a[mt] = ldh8(H1 + (size_t)(8192 + rows[mt])*512 + ki*32 + q*8);
    #pragma unroll
    for (int nt=0; nt<4; ++nt)
      b[nt] = ldh8(Bp + ((size_t)(ki*4+q)*5120 + vbase + nt*16 + m15)*8);
    #pragma unroll
    for (int mt=0; mt<4; ++mt)
      #pragma unroll
      for (int nt=0; nt<4; ++nt) acc[mt][nt] = MFMA_F16(a[mt], b[nt], acc[mt][nt]);
  }
  #pragma unroll
  for (int mt=0; mt<4; ++mt){
    int rowa[4], s0a[4], s1a[4];
    #pragma unroll
    for (int r=0; r<4; ++r){
      int row = rowbase + mt*16 + q*4 + r;
      rowa[r] = row;
      int rr = row < 8128 ? row : 8127;
      int i = rr >> 6, b = rr & 63;
      s0a[r] = src[i*64 + b];         // src[t-1], t = i+1
      s1a[r] = src[(i+1)*64 + b];     // src[t]
    }
    #pragma unroll
    for (int nt=0; nt<4; ++nt){
      int v = vbase + nt*16 + m15;
      if (v < 5000){
        float fb = fcb[v];
        #pragma unroll
        for (int r=0; r<4; ++r){
          if (rowa[r] < 8128){
            float d0 = vs[(size_t)s0a[r]*5000 + v];
            float d1 = vs[(size_t)s1a[r]*5000 + v];
            float d = fminf(fminf(d0, d1), 20.0f);
            float mult = (v==3 || v==4 || v==4999) ? 1.0f : (d*d - 20.0f*d + 1.0f);
            out[(size_t)(rowa[r] + 64)*5000 + v] = (acc[mt][nt][r] + fb)*mult;
          }
        }
      }
    }
  }
}

// ---------------- host launch ----------------
extern "C" void kernel_launch(void* const* d_in, const int* in_sizes, int n_in,
                              void* d_out, int out_size, void* d_ws, size_t ws_size,
                              hipStream_t stream) {
  (void)in_sizes; (void)n_in; (void)out_size; (void)ws_size;
  const int*   src   = (const int*)  d_in[0];
  const int*   trg   = (const int*)  d_in[2];
  const float* vs    = (const float*)d_in[4];
  const float* embE  = (const float*)d_in[5];
  const float* embD  = (const float*)d_in[6];
  const float* eWih0 = (const float*)d_in[7];
  const float* eWhh0 = (const float*)d_in[8];
  const float* eb0   = (const float*)d_in[9];
  const float* eWih1 = (const float*)d_in[10];
  const float* eWhh1 = (const float*)d_in[11];
  const float* eb1   = (const float*)d_in[12];
  const float* dWih0 = (const float*)d_in[13];
  const float* dWhh0 = (const float*)d_in[14];
  const float* db0   = (const float*)d_in[15];
  const float* dWih1 = (const float*)d_in[16];
  const float* dWhh1 = (const float*)d_in[17];
  const float* db1   = (const float*)d_in[18];
  const float* fcW   = (const float*)d_in[19];
  const float* fcb   = (const float*)d_in[20];
  float* out = (float*)d_out;
  char* ws = (char*)d_ws;

  init_kernel<<<1250, 256, 0, stream>>>(out, ws);
  pack_kernel<<<48944, 256, 0, stream>>>(ws, embE, embD,
      eWih0, eWhh0, eb0, eWih1, eWhh1, eb1,
      dWih0, dWhh0, db0, dWih1, dWhh1, db1, fcW);
  table_kernel<<<dim3(40,16,2), 256, 0, stream>>>(ws);
  seq_kernel<<<192, 256, 0, stream>>>(ws, src, trg);
  fc_kernel<<<dim3(64,40), 256, 0, stream>>>(ws, src, vs, fcb, out);
}

// Round 2
// 2599.281 us; speedup vs baseline: 1.9055x; 1.9055x over previous
//
#include <hip/hip_runtime.h>
#include <hip/hip_fp16.h>

typedef _Float16 f16;
typedef _Float16 half8 __attribute__((ext_vector_type(8)));
typedef _Float16 f16x2 __attribute__((ext_vector_type(2)));
typedef float floatx4 __attribute__((ext_vector_type(4)));

#define MFMA_F16(a,b,c) __builtin_amdgcn_mfma_f32_16x16x32_f16((a),(b),(c),0,0,0)

namespace cfg {
constexpr int V=5000, E=256, H=512, T=128, NB=64, G4=2048, VP=5120, NSTEPS=255;
// ws byte offsets (all 16B aligned)
constexpr size_t XPE = 0;                                  // f16 [V][2048] paired-col layout
constexpr size_t XPD = XPE + (size_t)V*G4*2;
constexpr size_t W0E = XPD + (size_t)V*G4*2;               // f16 [64][2048][8]  (Whh0 pack)
constexpr size_t W0D = W0E + (size_t)64*G4*8*2;
constexpr size_t W1E = W0D + (size_t)64*G4*8*2;            // f16 [128][2048][8] ([Wih1;Whh1] pack)
constexpr size_t W1D = W1E + (size_t)128*G4*8*2;
constexpr size_t WT0E= W1D + (size_t)128*G4*8*2;           // f16 [32][2048][8]  (Wih0 pack)
constexpr size_t WT0D= WT0E + (size_t)32*G4*8*2;
constexpr size_t FCW = WT0D + (size_t)32*G4*8*2;           // f16 [64][5120][8]  (fc_W pack)
constexpr size_t EMBE= FCW + (size_t)64*VP*8*2;            // f16 [V][256]
constexpr size_t EMBD= EMBE + (size_t)V*E*2;
constexpr size_t B0E = EMBD + (size_t)V*E*2;               // f32 [2048] permuted
constexpr size_t B0D = B0E + (size_t)G4*4;
constexpr size_t B1E = B0D + (size_t)G4*4;
constexpr size_t B1D = B1E + (size_t)G4*4;
constexpr size_t H0B = B1D + (size_t)G4*4;                 // f16 [255][64][512]
constexpr size_t H1B = H0B + (size_t)NSTEPS*NB*H*2;        // f16 [255][64][512]
constexpr size_t CNT = H1B + (size_t)NSTEPS*NB*H*2;        // int c0[256], c1[256]
}

__device__ __forceinline__ int gcol0(int p){ int s=p&31, w=p>>5; return ((s>>3)*512) + w*8 + (s&7); }
__device__ __forceinline__ int gcol1(int p){ int s=p&15, w=p>>4; return ((s>>2)*512) + w*4 + (s&3); }
__device__ __forceinline__ float sigf(float x){ return 1.0f/(1.0f + __expf(-x)); }
__device__ __forceinline__ half8 ldh8(const f16* p){ return *(const half8*)p; }

// ---------------- init: zero out[0,:,:] and counters ----------------
__global__ void init_kernel(float* out, char* ws){
  int i = blockIdx.x*256 + threadIdx.x;
  if (i < 320000) out[i] = 0.0f;
  if (i < 512) ((int*)(ws + cfg::CNT))[i] = 0;
}

// ---------------- pack/convert weights ----------------
__global__ void pack_kernel(char* ws,
    const float* embE, const float* embD,
    const float* eWih0, const float* eWhh0, const float* eb0,
    const float* eWih1, const float* eWhh1, const float* eb1,
    const float* dWih0, const float* dWhh0, const float* db0,
    const float* dWih1, const float* dWhh1, const float* db1,
    const float* fcW)
{
  long long idx = (long long)blockIdx.x*256 + threadIdx.x;
  if (idx < 1280000) { ((f16*)(ws+cfg::EMBE))[idx] = (f16)embE[idx]; return; }
  idx -= 1280000;
  if (idx < 1280000) { ((f16*)(ws+cfg::EMBD))[idx] = (f16)embD[idx]; return; }
  idx -= 1280000;
  if (idx < 2097152) { // Whh0 packs enc+dec: [k8][2048][8]
    int which = idx >= 1048576; long long t = idx & 1048575;
    int j = t&7, p = (int)((t>>3)&2047), k8 = (int)(t>>14);
    const float* W = which ? dWhh0 : eWhh0;
    f16* O = (f16*)(ws + (which ? cfg::W0D : cfg::W0E));
    O[t] = (f16)W[(long long)gcol0(p)*512 + k8*8 + j]; return; }
  idx -= 2097152;
  if (idx < 4194304) { // [Wih1;Whh1] packs: [k8(128)][2048][8]
    int which = idx >= 2097152; long long t = idx & 2097151;
    int j = t&7, p = (int)((t>>3)&2047), k8 = (int)(t>>14);
    int gc = gcol1(p); int k = k8*8 + j;
    const float* Wi = which ? dWih1 : eWih1;
    const float* Wh = which ? dWhh1 : eWhh1;
    f16* O = (f16*)(ws + (which ? cfg::W1D : cfg::W1E));
    O[t] = (f16)(k < 512 ? Wi[(long long)gc*512 + k] : Wh[(long long)gc*512 + (k-512)]); return; }
  idx -= 4194304;
  if (idx < 1048576) { // Wih0 packs: [k8(32)][2048][8]
    int which = idx >= 524288; long long t = idx & 524287;
    int j = t&7, p = (int)((t>>3)&2047), k8 = (int)(t>>14);
    const float* W = which ? dWih0 : eWih0;
    f16* O = (f16*)(ws + (which ? cfg::WT0D : cfg::WT0E));
    O[t] = (f16)W[(long long)gcol0(p)*256 + k8*8 + j]; return; }
  idx -= 1048576;
  if (idx < 2621440) { // fcW pack: [k8(64)][5120][8]
    long long t = idx; int j = t&7; int n = (int)((t>>3)%5120); int k8 = (int)(t/40960);
    ((f16*)(ws+cfg::FCW))[t] = (f16)(n < 5000 ? fcW[(long long)n*512 + k8*8 + j] : 0.0f); return; }
  idx -= 2621440;
  if (idx < 8192) {
    int which = (int)(idx>>11); int p = (int)(idx&2047);
    if      (which==0) ((float*)(ws+cfg::B0E))[p] = eb0[gcol0(p)];
    else if (which==1) ((float*)(ws+cfg::B0D))[p] = db0[gcol0(p)];
    else if (which==2) ((float*)(ws+cfg::B1E))[p] = eb1[gcol1(p)];
    else               ((float*)(ws+cfg::B1D))[p] = db1[gcol1(p)];
  }
}

// ---------------- XP tables: XP[v] = emb[v] @ Wih0^T + b0 ----------------
__global__ __launch_bounds__(256) void table_kernel(char* ws){
  int which = blockIdx.z;
  const f16* A  = (const f16*)(ws + (which ? cfg::EMBD : cfg::EMBE));
  const f16* Bp = (const f16*)(ws + (which ? cfg::WT0D : cfg::WT0E));
  const float* b0p = (const float*)(ws + (which ? cfg::B0D : cfg::B0E));
  f16* XP = (f16*)(ws + (which ? cfg::XPD : cfg::XPE));
  int lane = threadIdx.x & 63, wave = threadIdx.x >> 6;
  int m15 = lane & 15, q = lane >> 4;
  int wm = wave >> 1, wn = wave & 1;
  int rowbase = blockIdx.x*128 + wm*64;
  int pbase   = blockIdx.y*128 + wn*64;
  floatx4 zz = {0.f,0.f,0.f,0.f};
  floatx4 acc[4][4];
  #pragma unroll
  for (int mt=0; mt<4; ++mt)
    #pragma unroll
    for (int nt=0; nt<4; ++nt) acc[mt][nt] = zz;
  int rows[4];
  #pragma unroll
  for (int mt=0; mt<4; ++mt){ int r = rowbase + mt*16 + m15; rows[mt] = r < 5000 ? r : 4999; }
  for (int ki=0; ki<8; ++ki){
    half8 a[4], b[4];
    #pragma unroll
    for (int mt=0; mt<4; ++mt) a[mt] = ldh8(A + (size_t)rows[mt]*256 + ki*32 + q*8);
    #pragma unroll
    for (int nt=0; nt<4; ++nt) b[nt] = ldh8(Bp + ((size_t)(ki*4+q)*2048 + pbase + nt*16 + m15)*8);
    #pragma unroll
    for (int mt=0; mt<4; ++mt)
      #pragma unroll
      for (int nt=0; nt<4; ++nt) acc[mt][nt] = MFMA_F16(a[mt], b[nt], acc[mt][nt]);
  }
  #pragma unroll
  for (int nt=0; nt<4; ++nt){
    int p = pbase + nt*16 + m15;
    float bb = b0p[p];
    int s = p & 31;
    int tcol = (p>>5)*32 + (s < 16 ? s*2 : (s-16)*2 + 1);  // paired [i_j,g_j] / [f_j,o_j]
    #pragma unroll
    for (int mt=0; mt<4; ++mt)
      #pragma unroll
      for (int r=0; r<4; ++r){
        int v = rowbase + mt*16 + q*4 + r;
        if (v < 5000) XP[(size_t)v*2048 + tcol] = (f16)(acc[mt][nt][r] + bb);
      }
  }
}

// ---------------- persistent recurrence kernel ----------------
// Sync design (fence-free): h states are stored with relaxed AGENT-scope
// atomic u32 stores (write-through to the device coherence point). The
// s_waitcnt vmcnt(0) the compiler emits before s_barrier drains them; tid0's
// relaxed agent atomic counter increment therefore lands at the coherence
// point strictly after the h data. Readers poll the counter with relaxed
// agent atomic loads (L2-bypassing) and then read h with plain loads —
// safe because each step's h lines are fresh addresses, first touched by
// any reader only after the counter trips. NO fences → no per-step L2
// invalidate → weights/XP stay L2-resident.
__device__ __forceinline__ void wait_ge(int* p, int target){
  while (__hip_atomic_load(p, __ATOMIC_RELAXED, __HIP_MEMORY_SCOPE_AGENT) < target)
    __builtin_amdgcn_s_sleep(1);
}

__device__ __forceinline__ void st_h_pair(f16* addr, float hlo, float hhi){
  union { f16 v[2]; unsigned u; } pk;
  pk.v[0] = (f16)hlo; pk.v[1] = (f16)hhi;
  __hip_atomic_store((unsigned*)addr, pk.u, __ATOMIC_RELAXED, __HIP_MEMORY_SCOPE_AGENT);
}

__global__ __launch_bounds__(256,1) void seq_kernel(char* ws, const int* src, const int* trg){
  int lane = threadIdx.x & 63, wave = threadIdx.x >> 6;
  int m15 = lane & 15, q = lane >> 4;
  int* c0 = (int*)(ws + cfg::CNT);
  int* c1 = c0 + 256;
  f16* H0 = (f16*)(ws + cfg::H0B);
  f16* H1 = (f16*)(ws + cfg::H1B);

  if (blockIdx.x < 64) {
    // ======== team0: layer-0 chain. Each wave owns rows [16w,16w+16),
    // block owns h-cols [8*bx, 8*bx+8) (32 gate-cols). K=512 per wave. ========
    int w = blockIdx.x;
    float cst[4] = {0.f,0.f,0.f,0.f};   // c0 state: valid on lanes m15<8
    for (int seg=0; seg<2; ++seg){
      const f16* Wp = (const f16*)(ws + (seg ? cfg::W0D : cfg::W0E));
      const f16* XP = (const f16*)(ws + (seg ? cfg::XPD : cfg::XPE));
      const int* tok = seg ? trg : src;
      int nsteps = seg ? 127 : 128, gbase = seg ? 128 : 0;
      half8 breg[16][2];   // 128 VGPRs: full-K register-stationary weights
      #pragma unroll
      for (int ki=0; ki<16; ++ki)
        #pragma unroll
        for (int nt=0; nt<2; ++nt)
          breg[ki][nt] = ldh8(Wp + ((size_t)(ki*4 + q)*2048 + w*32 + nt*16 + m15)*8);
      for (int i=0; i<nsteps; ++i){
        int g = gbase + i;
        if (threadIdx.x == 0 && g > 0) wait_ge(c0 + g - 1, 64);
        __syncthreads();
        floatx4 acc0 = {0.f,0.f,0.f,0.f}, acc1 = {0.f,0.f,0.f,0.f};
        if (g > 0){
          const f16* hp = H0 + (size_t)(g-1)*32768 + (wave*16 + m15)*512;
          #pragma unroll
          for (int ki=0; ki<16; ++ki){
            half8 a = ldh8(hp + ki*32 + q*8);
            acc0 = MFMA_F16(a, breg[ki][0], acc0);
            acc1 = MFMA_F16(a, breg[ki][1], acc1);
          }
        }
        int4 tk = *(const int4*)(tok + i*64 + wave*16 + q*4);
        int tks[4] = {tk.x, tk.y, tk.z, tk.w};
        float gs0[4], gs1[4];
        #pragma unroll
        for (int r=0; r<4; ++r){
          f16x2 xp = *(const f16x2*)(XP + (size_t)tks[r]*2048 + w*32 + m15*2);
          gs0[r] = acc0[r] + (float)xp[0];  // i (m15<8) / f (m15>=8)
          gs1[r] = acc1[r] + (float)xp[1];  // g (m15<8) / o (m15>=8)
        }
        float fv[4], ov[4];
        #pragma unroll
        for (int r=0; r<4; ++r){ fv[r] = __shfl_xor(gs0[r], 8); ov[r] = __shfl_xor(gs1[r], 8); }
        f16* hout = H0 + (size_t)g*32768;
        #pragma unroll
        for (int r=0; r<4; ++r){
          float c = sigf(fv[r])*cst[r] + sigf(gs0[r])*tanhf(gs1[r]);
          cst[r] = c;                               // garbage-but-bounded on m15>=8
          float h = sigf(ov[r])*tanhf(c);
          float hp2 = __shfl_xor(h, 1);
          if (m15 < 8 && !(m15 & 1))
            st_h_pair(hout + (wave*16 + q*4 + r)*512 + w*8 + m15, h, hp2);
        }
        __syncthreads();   // drains all waves' write-through stores (vmcnt 0)
        if (threadIdx.x == 0)
          __hip_atomic_fetch_add(c0 + g, 1, __ATOMIC_RELAXED, __HIP_MEMORY_SCOPE_AGENT);
      }
    }
  } else {
    // ======== team1: layer-1, trails one step. Each wave owns rows
    // [16w,16w+16), block owns h-cols [4*bx,4*bx+4). K=1024 per wave. ========
    int w = blockIdx.x - 64;   // 0..127
    float cst[4] = {0.f,0.f,0.f,0.f};   // c1 state: valid on lanes m15<4
    for (int seg=0; seg<2; ++seg){
      const f16* Wp = (const f16*)(ws + (seg ? cfg::W1D : cfg::W1E));
      const float* bp = (const float*)(ws + (seg ? cfg::B1D : cfg::B1E));
      int nsteps = seg ? 127 : 128, gbase = seg ? 128 : 0;
      half8 breg[32];      // 128 VGPRs: [Wih1;Whh1] K=1024, 16 gate-cols
      #pragma unroll
      for (int ki=0; ki<32; ++ki)
        breg[ki] = ldh8(Wp + ((size_t)(ki*4 + q)*2048 + w*16 + m15)*8);
      float b1v = bp[w*16 + m15];
      for (int i=0; i<nsteps; ++i){
        int g = gbase + i;
        if (threadIdx.x == 0){
          wait_ge(c0 + g, 64);
          if (g > 0) wait_ge(c1 + g - 1, 128);
        }
        __syncthreads();
        floatx4 acc = {0.f,0.f,0.f,0.f};
        const f16* hp0 = H0 + (size_t)g*32768 + (wave*16 + m15)*512;
        #pragma unroll
        for (int ki=0; ki<16; ++ki){
          half8 a = ldh8(hp0 + ki*32 + q*8);
          acc = MFMA_F16(a, breg[ki], acc);
        }
        if (g > 0){
          const f16* hp1 = H1 + (size_t)(g-1)*32768 + (wave*16 + m15)*512;
          #pragma unroll
          for (int ki=0; ki<16; ++ki){
            half8 a = ldh8(hp1 + ki*32 + q*8);
            acc = MFMA_F16(a, breg[ki+16], acc);
          }
        }
        float gs[4];
        #pragma unroll
        for (int r=0; r<4; ++r) gs[r] = acc[r] + b1v;
        float f4[4], g8[4], o12[4];
        #pragma unroll
        for (int r=0; r<4; ++r){
          f4[r]  = __shfl_xor(gs[r], 4);
          g8[r]  = __shfl_xor(gs[r], 8);
          o12[r] = __shfl_xor(gs[r], 12);
        }
        f16* hout = H1 + (size_t)g*32768;
        #pragma unroll
        for (int r=0; r<4; ++r){
          float c = sigf(f4[r])*cst[r] + sigf(gs[r])*tanhf(g8[r]);
          cst[r] = c;
          float h = sigf(o12[r])*tanhf(c);
          float hp2 = __shfl_xor(h, 1);
          if (m15 < 4 && !(m15 & 1))
            st_h_pair(hout + (wave*16 + q*4 + r)*512 + w*4 + m15, h, hp2);
        }
        __syncthreads();
        if (threadIdx.x == 0)
          __hip_atomic_fetch_add(c1 + g, 1, __ATOMIC_RELAXED, __HIP_MEMORY_SCOPE_AGENT);
      }
    }
  }
}

// ---------------- fc projection + vocab_sim mask epilogue ----------------
__global__ __launch_bounds__(256) void fc_kernel(char* ws, const int* src, const float* vs,
                                                 const float* fcb, float* out){
  const f16* H1 = (const f16*)(ws + cfg::H1B);
  const f16* Bp = (const f16*)(ws + cfg::FCW);
  int lane = threadIdx.x & 63, wave = threadIdx.x >> 6;
  int m15 = lane & 15, q = lane >> 4;
  int wm = wave >> 1, wn = wave & 1;
  int rowbase = blockIdx.x*128 + wm*64;
  int vbase   = blockIdx.y*128 + wn*64;
  floatx4 zz = {0.f,0.f,0.f,0.f};
  floatx4 acc[4][4];
  #pragma unroll
  for (int mt=0; mt<4; ++mt)
    #pragma unroll
    for (int nt=0; nt<4; ++nt) acc[mt][nt] = zz;
  int rows[4];
  #pragma unroll
  for (int mt=0; mt<4; ++mt){ int r = rowbase + mt*16 + m15; rows[mt] = r < 8128 ? r : 8127; }
  for (int ki=0; ki<16; ++ki){
    half8 a[4], b[4];
    #pragma unroll
    for (int mt=0; mt<4; ++mt)
      a[mt] = ldh8(H1 + (size_t)(8192 + rows[mt])*512 + ki*32 + q*8);
    #pragma unroll
    for (int nt=0; nt<4; ++nt)
      b[nt] = ldh8(Bp + ((size_t)(ki*4+q)*5120 + vbase + nt*16 + m15)*8);
    #pragma unroll
    for (int mt=0; mt<4; ++mt)
      #pragma unroll
      for (int nt=0; nt<4; ++nt) acc[mt][nt] = MFMA_F16(a[mt], b[nt], acc[mt][nt]);
  }
  #pragma unroll
  for (int mt=0; mt<4; ++mt){
    int rowa[4], s0a[4], s1a[4];
    #pragma unroll
    for (int r=0; r<4; ++r){
      int row = rowbase + mt*16 + q*4 + r;
      rowa[r] = row;
      int rr = row < 8128 ? row : 8127;
      int i = rr >> 6, b = rr & 63;
      s0a[r] = src[i*64 + b];         // src[t-1], t = i+1
      s1a[r] = src[(i+1)*64 + b];     // src[t]
    }
    #pragma unroll
    for (int nt=0; nt<4; ++nt){
      int v = vbase + nt*16 + m15;
      if (v < 5000){
        float fb = fcb[v];
        #pragma unroll
        for (int r=0; r<4; ++r){
          if (rowa[r] < 8128){
            float d0 = vs[(size_t)s0a[r]*5000 + v];
            float d1 = vs[(size_t)s1a[r]*5000 + v];
            float d = fminf(fminf(d0, d1), 20.0f);
            float mult = (v==3 || v==4 || v==4999) ? 1.0f : (d*d - 20.0f*d + 1.0f);
            out[(size_t)(rowa[r] + 64)*5000 + v] = (acc[mt][nt][r] + fb)*mult;
          }
        }
      }
    }
  }
}

// ---------------- host launch ----------------
extern "C" void kernel_launch(void* const* d_in, const int* in_sizes, int n_in,
                              void* d_out, int out_size, void* d_ws, size_t ws_size,
                              hipStream_t stream) {
  (void)in_sizes; (void)n_in; (void)out_size; (void)ws_size;
  const int*   src   = (const int*)  d_in[0];
  const int*   trg   = (const int*)  d_in[2];
  const float* vs    = (const float*)d_in[4];
  const float* embE  = (const float*)d_in[5];
  const float* embD  = (const float*)d_in[6];
  const float* eWih0 = (const float*)d_in[7];
  const float* eWhh0 = (const float*)d_in[8];
  const float* eb0   = (const float*)d_in[9];
  const float* eWih1 = (const float*)d_in[10];
  const float* eWhh1 = (const float*)d_in[11];
  const float* eb1   = (const float*)d_in[12];
  const float* dWih0 = (const float*)d_in[13];
  const float* dWhh0 = (const float*)d_in[14];
  const float* db0   = (const float*)d_in[15];
  const float* dWih1 = (const float*)d_in[16];
  const float* dWhh1 = (const float*)d_in[17];
  const float* db1   = (const float*)d_in[18];
  const float* fcW   = (const float*)d_in[19];
  const float* fcb   = (const float*)d_in[20];
  float* out = (float*)d_out;
  char* ws = (char*)d_ws;

  init_kernel<<<1250, 256, 0, stream>>>(out, ws);
  pack_kernel<<<48944, 256, 0, stream>>>(ws, embE, embD,
      eWih0, eWhh0, eb0, eWih1, eWhh1, eb1,
      dWih0, dWhh0, db0, dWih1, dWhh1, db1, fcW);
  table_kernel<<<dim3(40,16,2), 256, 0, stream>>>(ws);
  seq_kernel<<<192, 256, 0, stream>>>(ws, src, trg);
  fc_kernel<<<dim3(64,40), 256, 0, stream>>>(ws, src, vs, fcb, out);
}